// Round 1
// baseline (62.287 us; speedup 1.0000x reference)
//
#include <hip/hip_runtime.h>

#define RES_V 16
#define RES_H 32
#define NS    100
#define GRD   256
#define NCH   11

__device__ __forceinline__ int iclamp(int x, int lo, int hi) {
    return x < lo ? lo : (x > hi ? hi : x);
}

__global__ __launch_bounds__(128) void sglv_render_kernel(
    const float* __restrict__ origin,
    const float* __restrict__ SGLV,
    const float* __restrict__ vrange,
    float* __restrict__ out)
{
    const int ray  = blockIdx.x;      // 0..511
    const int v    = ray >> 5;
    const int u    = ray & 31;
    const int tid  = threadIdx.x;     // 0..127
    const int lane = tid & 63;
    const int wid  = tid >> 6;

    __shared__ float s_wave0;             // wave0 total transmittance factor
    __shared__ float s_red[2][NCH];       // per-wave channel partial sums

    // ---- direction (computed in f64 for accuracy, cast to f32) ----
    const double PI = 3.14159265358979323846;
    double phi   = 2.0 * PI * (double)u / (double)RES_H;
    double theta = PI * (double)v / (double)RES_V;
    double st = sin(theta);
    double dx = st * cos(phi);
    double dy = cos(theta);
    double dz = st * sin(phi);
    double nrm = sqrt(dx*dx + dy*dy + dz*dz);
    nrm = nrm > 1e-12 ? nrm : 1e-12;
    float d[3] = { (float)(dx/nrm), (float)(dy/nrm), (float)(dz/nrm) };

    float org[3] = { origin[0], origin[1], origin[2] };
    float vr0[3] = { vrange[0], vrange[1], vrange[2] };
    float vr1[3] = { vrange[3], vrange[4], vrange[5] };

    // ---- ray-box (matches reference slab logic incl. strict >0 and ±inf) ----
    const float INF = __builtin_inff();
    float t0 = INF, t1 = INF;
    #pragma unroll
    for (int k = 0; k < 3; ++k) {
        float num0 = vr0[k] - org[k];
        float num1 = vr1[k] - org[k];
        float tmin, tmax;
        if (d[k] == 0.0f) {
            tmin = (num0 > 0.0f) ? INF : -INF;
            tmax = (num1 > 0.0f) ? INF : -INF;
        } else {
            tmin = num0 / d[k];
            tmax = num1 / d[k];
        }
        t0 = fminf(t0, (tmin > 0.0f) ? tmin : INF);
        t1 = fminf(t1, (tmax > 0.0f) ? tmax : INF);
    }
    float t_end   = fminf(t0, t1);
    float t_start = 0.0f;

    // ---- per-sample trilinear interpolation (thread = sample) ----
    float samp[NCH];
    #pragma unroll
    for (int c = 0; c < NCH; ++c) samp[c] = 0.0f;

    float fac = 1.0f;   // (1 - alpha + 1e-10); 1.0 for padding threads
    if (tid < NS) {
        float lin = (float)tid / (float)(NS - 1);
        float t = t_start + lin * (t_end - t_start);

        float np_[3];
        #pragma unroll
        for (int k = 0; k < 3; ++k) {
            float p = org[k] + t * d[k];
            np_[k] = (p - vr0[k]) / (vr1[k] - vr0[k]) * 2.0f - 1.0f;
        }
        float ix = (np_[0] + 1.0f) * 0.5f * (float)(GRD - 1);
        float iy = (np_[1] + 1.0f) * 0.5f * (float)(GRD - 1);
        float iz = (np_[2] + 1.0f) * 0.5f * (float)(GRD - 1);
        float x0f = floorf(ix), y0f = floorf(iy), z0f = floorf(iz);
        float fx = ix - x0f, fy = iy - y0f, fz = iz - z0f;
        int x0 = (int)x0f, y0 = (int)y0f, z0 = (int)z0f;

        const size_t CS = (size_t)GRD * GRD * GRD;

        #pragma unroll
        for (int cz = 0; cz < 2; ++cz) {
            #pragma unroll
            for (int cy = 0; cy < 2; ++cy) {
                #pragma unroll
                for (int cx = 0; cx < 2; ++cx) {
                    int xi = x0 + cx, yi = y0 + cy, zi = z0 + cz;
                    float w = (cx ? fx : 1.0f - fx)
                            * (cy ? fy : 1.0f - fy)
                            * (cz ? fz : 1.0f - fz);
                    bool valid = ((unsigned)xi < GRD) & ((unsigned)yi < GRD)
                               & ((unsigned)zi < GRD);
                    w = valid ? w : 0.0f;
                    int xc = iclamp(xi, 0, GRD - 1);
                    int yc = iclamp(yi, 0, GRD - 1);
                    int zc = iclamp(zi, 0, GRD - 1);
                    size_t base = ((size_t)zc * GRD + (size_t)yc) * GRD + (size_t)xc;
                    // unconditional loads (clamped addr, w=0 masks) -> max MLP
                    #pragma unroll
                    for (int c = 0; c < NCH; ++c)
                        samp[c] = fmaf(w, SGLV[(size_t)c * CS + base], samp[c]);
                }
            }
        }
        fac = (1.0f - samp[3]) + 1e-10f;
    }

    // ---- inclusive prefix product of fac across samples (cumprod) ----
    float p = fac;
    #pragma unroll
    for (int off = 1; off < 64; off <<= 1) {
        float o = __shfl_up(p, off, 64);
        if (lane >= off) p *= o;
    }
    if (wid == 0 && lane == 63) s_wave0 = p;
    __syncthreads();
    if (wid == 1) p *= s_wave0;

    float T = p;                       // transmittance (inclusive)
    float wgt = (tid < NS) ? samp[3] * T : 0.0f;

    // ---- deterministic channel reduction: wave butterfly + LDS combine ----
    #pragma unroll
    for (int c = 0; c < NCH; ++c) {
        float val = wgt * samp[c];
        #pragma unroll
        for (int off = 32; off > 0; off >>= 1)
            val += __shfl_xor(val, off, 64);
        if (lane == 0) s_red[wid][c] = val;
    }
    __syncthreads();

    if (tid == 0) {
        float acc[NCH];
        #pragma unroll
        for (int c = 0; c < NCH; ++c) acc[c] = s_red[0][c] + s_red[1][c];

        float sdd = d[0] * acc[8] + d[1] * acc[9] + d[2] * acc[10];
        float e = expf(acc[7] * (sdd - 1.0f));
        int pix = v * RES_H + u;
        out[0 * RES_V * RES_H + pix] = acc[0] + acc[4] * e;
        out[1 * RES_V * RES_H + pix] = acc[1] + acc[5] * e;
        out[2 * RES_V * RES_H + pix] = acc[2] + acc[6] * e;
    }
}

extern "C" void kernel_launch(void* const* d_in, const int* in_sizes, int n_in,
                              void* d_out, int out_size, void* d_ws, size_t ws_size,
                              hipStream_t stream) {
    const float* origin = (const float*)d_in[0];
    const float* SGLV   = (const float*)d_in[1];
    const float* vrange = (const float*)d_in[2];
    float* out = (float*)d_out;

    sglv_render_kernel<<<dim3(RES_V * RES_H), dim3(128), 0, stream>>>(
        origin, SGLV, vrange, out);
}

// Round 2
// 49.242 us; speedup vs baseline: 1.2649x; 1.2649x over previous
//
#include <hip/hip_runtime.h>

#define RES_V 16
#define RES_H 32
#define NS    100
#define GRD   256
#define NCH   11

__device__ __forceinline__ int iclamp(int x, int lo, int hi) {
    return x < lo ? lo : (x > hi ? hi : x);
}

// One block per ray. 1024 threads = 128 sample-groups x 8 corners.
// thread tid: sample s = tid>>3 (active if s < NS), corner = tid&7.
__global__ __launch_bounds__(1024) void sglv_render_kernel(
    const float* __restrict__ origin,
    const float* __restrict__ SGLV,
    const float* __restrict__ vrange,
    float* __restrict__ out)
{
    const int ray    = blockIdx.x;      // 0..511
    const int v      = ray >> 5;
    const int u      = ray & 31;
    const int tid    = threadIdx.x;     // 0..1023
    const int lane   = tid & 63;
    const int wid    = tid >> 6;        // 0..15
    const int s      = tid >> 3;        // sample index 0..127
    const int corner = tid & 7;         // cx = bit0, cy = bit1, cz = bit2

    __shared__ float s_wtot[16];        // per-wave transmittance factor
    __shared__ float s_red[16][NCH];    // per-wave channel partial sums

    // ---- direction (f32, matches reference's f32 trig within ulps) ----
    const float PIF = 3.14159265358979323846f;
    float phi   = (2.0f * PIF / (float)RES_H) * (float)u;
    float theta = (PIF / (float)RES_V) * (float)v;
    float stv = sinf(theta);
    float dx0 = stv * cosf(phi);
    float dy0 = cosf(theta);
    float dz0 = stv * sinf(phi);
    float nrm = sqrtf(dx0 * dx0 + dy0 * dy0 + dz0 * dz0);
    nrm = fmaxf(nrm, 1e-12f);
    float d[3] = { dx0 / nrm, dy0 / nrm, dz0 / nrm };

    float org[3] = { origin[0], origin[1], origin[2] };
    float vr0[3] = { vrange[0], vrange[1], vrange[2] };
    float vr1[3] = { vrange[3], vrange[4], vrange[5] };

    // ---- ray-box (reference slab logic incl. strict >0 and +-inf) ----
    const float INF = __builtin_inff();
    float t0 = INF, t1 = INF;
    #pragma unroll
    for (int k = 0; k < 3; ++k) {
        float num0 = vr0[k] - org[k];
        float num1 = vr1[k] - org[k];
        float tmin, tmax;
        if (d[k] == 0.0f) {
            tmin = (num0 > 0.0f) ? INF : -INF;
            tmax = (num1 > 0.0f) ? INF : -INF;
        } else {
            tmin = num0 / d[k];
            tmax = num1 / d[k];
        }
        t0 = fminf(t0, (tmin > 0.0f) ? tmin : INF);
        t1 = fminf(t1, (tmax > 0.0f) ? tmax : INF);
    }
    float t_end   = fminf(t0, t1);
    float t_start = 0.0f;

    // ---- per-(sample,corner) gather: 11 independent loads ----
    float samp[NCH];
    #pragma unroll
    for (int c = 0; c < NCH; ++c) samp[c] = 0.0f;

    const bool act = (s < NS);
    if (act) {
        float lin = (float)s / (float)(NS - 1);
        float t = t_start + lin * (t_end - t_start);

        float np_[3];
        #pragma unroll
        for (int k = 0; k < 3; ++k) {
            float p = org[k] + t * d[k];
            np_[k] = (p - vr0[k]) / (vr1[k] - vr0[k]) * 2.0f - 1.0f;
        }
        float ix = (np_[0] + 1.0f) * 0.5f * (float)(GRD - 1);
        float iy = (np_[1] + 1.0f) * 0.5f * (float)(GRD - 1);
        float iz = (np_[2] + 1.0f) * 0.5f * (float)(GRD - 1);
        float x0f = floorf(ix), y0f = floorf(iy), z0f = floorf(iz);
        float fx = ix - x0f, fy = iy - y0f, fz = iz - z0f;
        int x0 = (int)x0f, y0 = (int)y0f, z0 = (int)z0f;

        int cx = corner & 1, cy = (corner >> 1) & 1, cz = corner >> 2;
        int xi = x0 + cx, yi = y0 + cy, zi = z0 + cz;
        float w = (cx ? fx : 1.0f - fx)
                * (cy ? fy : 1.0f - fy)
                * (cz ? fz : 1.0f - fz);
        bool valid = ((unsigned)xi < GRD) & ((unsigned)yi < GRD)
                   & ((unsigned)zi < GRD);
        w = valid ? w : 0.0f;
        int xc = iclamp(xi, 0, GRD - 1);
        int yc = iclamp(yi, 0, GRD - 1);
        int zc = iclamp(zi, 0, GRD - 1);
        const size_t CS = (size_t)GRD * GRD * GRD;
        size_t base = ((size_t)zc * GRD + (size_t)yc) * GRD + (size_t)xc;

        #pragma unroll
        for (int c = 0; c < NCH; ++c)
            samp[c] = w * SGLV[(size_t)c * CS + base];
    }

    // ---- reduce 8 corners (low 3 lane bits) -> full trilerp value ----
    #pragma unroll
    for (int c = 0; c < NCH; ++c) {
        #pragma unroll
        for (int off = 1; off < 8; off <<= 1)
            samp[c] += __shfl_xor(samp[c], off, 64);
    }

    // ---- inclusive cumprod over samples ----
    // all 8 lanes of a sample-group carry the same fac -> group-uniform scan
    float fac = act ? (1.0f - samp[3]) + 1e-10f : 1.0f;
    float p = fac;
    #pragma unroll
    for (int off = 8; off < 64; off <<= 1) {
        float o = __shfl_up(p, off, 64);
        if (lane >= off) p *= o;
    }
    if (lane == 63) s_wtot[wid] = p;
    __syncthreads();
    float pre = 1.0f;
    for (int w2 = 0; w2 < wid; ++w2) pre *= s_wtot[w2];

    float T   = pre * p;                 // inclusive transmittance
    float wgt = act ? samp[3] * T : 0.0f;
    float sel = (corner == 0) ? wgt : 0.0f;   // count each sample once

    // ---- deterministic channel reduction ----
    #pragma unroll
    for (int c = 0; c < NCH; ++c) {
        float val = sel * samp[c];
        #pragma unroll
        for (int off = 32; off > 0; off >>= 1)
            val += __shfl_xor(val, off, 64);
        if (lane == 0) s_red[wid][c] = val;
    }
    __syncthreads();

    if (tid == 0) {
        float acc[NCH];
        #pragma unroll
        for (int c = 0; c < NCH; ++c) {
            float a = 0.0f;
            #pragma unroll
            for (int w2 = 0; w2 < 16; ++w2) a += s_red[w2][c];
            acc[c] = a;
        }
        float sdd = d[0] * acc[8] + d[1] * acc[9] + d[2] * acc[10];
        float e = expf(acc[7] * (sdd - 1.0f));
        int pix = v * RES_H + u;
        out[0 * RES_V * RES_H + pix] = acc[0] + acc[4] * e;
        out[1 * RES_V * RES_H + pix] = acc[1] + acc[5] * e;
        out[2 * RES_V * RES_H + pix] = acc[2] + acc[6] * e;
    }
}

extern "C" void kernel_launch(void* const* d_in, const int* in_sizes, int n_in,
                              void* d_out, int out_size, void* d_ws, size_t ws_size,
                              hipStream_t stream) {
    const float* origin = (const float*)d_in[0];
    const float* SGLV   = (const float*)d_in[1];
    const float* vrange = (const float*)d_in[2];
    float* out = (float*)d_out;

    sglv_render_kernel<<<dim3(RES_V * RES_H), dim3(1024), 0, stream>>>(
        origin, SGLV, vrange, out);
}

// Round 3
// 20.191 us; speedup vs baseline: 3.0849x; 2.4388x over previous
//
#include <hip/hip_runtime.h>

#define RES_V 16
#define RES_H 32
#define NS    100
#define GRD   256
#define NCH   11
#define NW    13            // waves per block (104 sample-groups >= 100)
#define BLK   (NW * 64)     // 832 threads

__device__ __forceinline__ int iclamp(int x, int lo, int hi) {
    return x < lo ? lo : (x > hi ? hi : x);
}

// One block per ray. Thread = (sample, corner): s = tid>>3, corner = tid&7.
// Phase A: gather alpha only (ch 3) for all samples -> cumprod -> T per sample.
// Phase B: gather remaining 10 channels only where T > EPS (prefix of samples).
__global__ __launch_bounds__(BLK) void sglv_render_kernel(
    const float* __restrict__ origin,
    const float* __restrict__ SGLV,
    const float* __restrict__ vrange,
    float* __restrict__ out)
{
    const int ray    = blockIdx.x;      // 0..511
    const int v      = ray >> 5;
    const int u      = ray & 31;
    const int tid    = threadIdx.x;     // 0..831
    const int lane   = tid & 63;
    const int wid    = tid >> 6;        // 0..12
    const int s      = tid >> 3;        // sample 0..103
    const int corner = tid & 7;         // cx=bit0, cy=bit1, cz=bit2

    __shared__ float s_wtot[NW];        // per-wave transmittance factor
    __shared__ float s_red[NW][NCH];    // per-wave channel partial sums

    // ---- direction (f32 trig; validated absmax 0.0 in round 2) ----
    const float PIF = 3.14159265358979323846f;
    float phi   = (2.0f * PIF / (float)RES_H) * (float)u;
    float theta = (PIF / (float)RES_V) * (float)v;
    float stv = sinf(theta);
    float dx0 = stv * cosf(phi);
    float dy0 = cosf(theta);
    float dz0 = stv * sinf(phi);
    float nrm = sqrtf(dx0 * dx0 + dy0 * dy0 + dz0 * dz0);
    nrm = fmaxf(nrm, 1e-12f);
    float d[3] = { dx0 / nrm, dy0 / nrm, dz0 / nrm };

    float org[3] = { origin[0], origin[1], origin[2] };
    float vr0[3] = { vrange[0], vrange[1], vrange[2] };
    float vr1[3] = { vrange[3], vrange[4], vrange[5] };

    // ---- ray-box (reference slab logic incl. strict >0 and +-inf) ----
    const float INF = __builtin_inff();
    float t0 = INF, t1 = INF;
    #pragma unroll
    for (int k = 0; k < 3; ++k) {
        float num0 = vr0[k] - org[k];
        float num1 = vr1[k] - org[k];
        float tmin, tmax;
        if (d[k] == 0.0f) {
            tmin = (num0 > 0.0f) ? INF : -INF;
            tmax = (num1 > 0.0f) ? INF : -INF;
        } else {
            tmin = num0 / d[k];
            tmax = num1 / d[k];
        }
        t0 = fminf(t0, (tmin > 0.0f) ? tmin : INF);
        t1 = fminf(t1, (tmax > 0.0f) ? tmax : INF);
    }
    float t_end   = fminf(t0, t1);
    float t_start = 0.0f;

    // ---- per-(sample,corner) address + weight; gather alpha only ----
    const size_t CS = (size_t)GRD * GRD * GRD;
    const bool act = (s < NS);
    float  w = 0.0f;
    size_t base = 0;
    float  alpha_part = 0.0f;

    if (act) {
        float lin = (float)s / (float)(NS - 1);
        float t = t_start + lin * (t_end - t_start);

        float np_[3];
        #pragma unroll
        for (int k = 0; k < 3; ++k) {
            float p = org[k] + t * d[k];
            np_[k] = (p - vr0[k]) / (vr1[k] - vr0[k]) * 2.0f - 1.0f;
        }
        float ix = (np_[0] + 1.0f) * 0.5f * (float)(GRD - 1);
        float iy = (np_[1] + 1.0f) * 0.5f * (float)(GRD - 1);
        float iz = (np_[2] + 1.0f) * 0.5f * (float)(GRD - 1);
        float x0f = floorf(ix), y0f = floorf(iy), z0f = floorf(iz);
        float fx = ix - x0f, fy = iy - y0f, fz = iz - z0f;
        int x0 = (int)x0f, y0 = (int)y0f, z0 = (int)z0f;

        int cx = corner & 1, cy = (corner >> 1) & 1, cz = corner >> 2;
        int xi = x0 + cx, yi = y0 + cy, zi = z0 + cz;
        w = (cx ? fx : 1.0f - fx)
          * (cy ? fy : 1.0f - fy)
          * (cz ? fz : 1.0f - fz);
        bool valid = ((unsigned)xi < GRD) & ((unsigned)yi < GRD)
                   & ((unsigned)zi < GRD);
        w = valid ? w : 0.0f;
        int xc = iclamp(xi, 0, GRD - 1);
        int yc = iclamp(yi, 0, GRD - 1);
        int zc = iclamp(zi, 0, GRD - 1);
        base = ((size_t)zc * GRD + (size_t)yc) * GRD + (size_t)xc;

        alpha_part = w * SGLV[3 * CS + base];
    }

    // ---- corner-reduce alpha (low 3 lane bits) ----
    float alpha = alpha_part;
    #pragma unroll
    for (int off = 1; off < 8; off <<= 1)
        alpha += __shfl_xor(alpha, off, 64);

    // ---- inclusive cumprod over samples (group-uniform scan) ----
    float fac = act ? (1.0f - alpha) + 1e-10f : 1.0f;
    float p = fac;
    #pragma unroll
    for (int off = 8; off < 64; off <<= 1) {
        float o = __shfl_up(p, off, 64);
        if (lane >= off) p *= o;
    }
    if (lane == 63) s_wtot[wid] = p;
    __syncthreads();
    float pre = 1.0f;
    for (int w2 = 0; w2 < wid; ++w2) pre *= s_wtot[w2];

    float T   = pre * p;                      // inclusive transmittance
    float wgt = act ? alpha * T : 0.0f;       // sample weight

    // ---- phase B: gather remaining channels only for live samples ----
    // tail error bound: sum_{dead} wgt*samp <= NS * EPS = 1e-6 << 1.2e-2
    const float EPS = 1e-8f;
    const bool live = act && (T > EPS);

    float samp[NCH];
    #pragma unroll
    for (int c = 0; c < NCH; ++c) samp[c] = 0.0f;
    samp[3] = alpha_part;                     // pre-reduce value (reduced below)

    if (live) {
        #pragma unroll
        for (int c = 0; c < NCH; ++c) {
            if (c == 3) continue;
            samp[c] = w * SGLV[(size_t)c * CS + base];
        }
    }

    // ---- corner-reduce all channels ----
    #pragma unroll
    for (int c = 0; c < NCH; ++c) {
        #pragma unroll
        for (int off = 1; off < 8; off <<= 1)
            samp[c] += __shfl_xor(samp[c], off, 64);
    }

    float sel = (corner == 0) ? wgt : 0.0f;   // count each sample once

    // ---- deterministic channel reduction ----
    #pragma unroll
    for (int c = 0; c < NCH; ++c) {
        float val = sel * samp[c];
        #pragma unroll
        for (int off = 32; off > 0; off >>= 1)
            val += __shfl_xor(val, off, 64);
        if (lane == 0) s_red[wid][c] = val;
    }
    __syncthreads();

    if (tid == 0) {
        float acc[NCH];
        #pragma unroll
        for (int c = 0; c < NCH; ++c) {
            float a = 0.0f;
            #pragma unroll
            for (int w2 = 0; w2 < NW; ++w2) a += s_red[w2][c];
            acc[c] = a;
        }
        float sdd = d[0] * acc[8] + d[1] * acc[9] + d[2] * acc[10];
        float e = expf(acc[7] * (sdd - 1.0f));
        int pix = v * RES_H + u;
        out[0 * RES_V * RES_H + pix] = acc[0] + acc[4] * e;
        out[1 * RES_V * RES_H + pix] = acc[1] + acc[5] * e;
        out[2 * RES_V * RES_H + pix] = acc[2] + acc[6] * e;
    }
}

extern "C" void kernel_launch(void* const* d_in, const int* in_sizes, int n_in,
                              void* d_out, int out_size, void* d_ws, size_t ws_size,
                              hipStream_t stream) {
    const float* origin = (const float*)d_in[0];
    const float* SGLV   = (const float*)d_in[1];
    const float* vrange = (const float*)d_in[2];
    float* out = (float*)d_out;

    sglv_render_kernel<<<dim3(RES_V * RES_H), dim3(BLK), 0, stream>>>(
        origin, SGLV, vrange, out);
}

// Round 4
// 15.143 us; speedup vs baseline: 4.1134x; 1.3334x over previous
//
#include <hip/hip_runtime.h>

#define RES_V 16
#define RES_H 32
#define NS    100
#define GRD   256
#define NCH   11
#define NW    13            // waves per block (104 sample-groups >= 100)
#define BLK   (NW * 64)     // 832 threads
#define CHUNKW 3            // phase-A chunk: waves 0..2 -> samples 0..23
#define EPS   1e-5f         // dead-sample threshold (err <= ~1e-4 << 1.2e-2)

__device__ __forceinline__ int iclamp(int x, int lo, int hi) {
    return x < lo ? lo : (x > hi ? hi : x);
}

__device__ __forceinline__ float corner_reduce(float x) {
    x += __shfl_xor(x, 1, 64);
    x += __shfl_xor(x, 2, 64);
    x += __shfl_xor(x, 4, 64);
    return x;
}

// inclusive product scan across the 8 sample-groups of a wave
// (fac is uniform within each 8-lane group)
__device__ __forceinline__ float group_scan(float fac, int lane) {
    float p = fac;
    #pragma unroll
    for (int off = 8; off < 64; off <<= 1) {
        float o = __shfl_up(p, off, 64);
        if (lane >= off) p *= o;
    }
    return p;
}

// One block per ray. Thread = (sample, corner): s = tid>>3, corner = tid&7.
// Phase A (chunked): alpha gathers for samples 0..23 only; dynamic fallback
// to the full range if transmittance hasn't died (block-uniform branch).
// Phase B: remaining 10 channels gathered only where T > EPS.
__global__ __launch_bounds__(BLK) void sglv_render_kernel(
    const float* __restrict__ origin,
    const float* __restrict__ SGLV,
    const float* __restrict__ vrange,
    float* __restrict__ out)
{
    const int ray    = blockIdx.x;      // 0..511
    const int v      = ray >> 5;
    const int u      = ray & 31;
    const int tid    = threadIdx.x;     // 0..831
    const int lane   = tid & 63;
    const int wid    = tid >> 6;        // 0..12
    const int s      = tid >> 3;        // sample 0..103
    const int corner = tid & 7;         // cx=bit0, cy=bit1, cz=bit2

    __shared__ float s_wtot[NW];        // per-wave transmittance factor
    __shared__ float s_red[NW][NCH];    // per-wave channel partial sums

    // ---- direction (f32 trig; validated absmax 0.0 in rounds 2-3) ----
    const float PIF = 3.14159265358979323846f;
    float phi   = (2.0f * PIF / (float)RES_H) * (float)u;
    float theta = (PIF / (float)RES_V) * (float)v;
    float stv = sinf(theta);
    float dx0 = stv * cosf(phi);
    float dy0 = cosf(theta);
    float dz0 = stv * sinf(phi);
    float nrm = sqrtf(dx0 * dx0 + dy0 * dy0 + dz0 * dz0);
    nrm = fmaxf(nrm, 1e-12f);
    float d[3] = { dx0 / nrm, dy0 / nrm, dz0 / nrm };

    float org[3] = { origin[0], origin[1], origin[2] };
    float vr0[3] = { vrange[0], vrange[1], vrange[2] };
    float vr1[3] = { vrange[3], vrange[4], vrange[5] };

    // ---- ray-box (reference slab logic incl. strict >0 and +-inf) ----
    const float INF = __builtin_inff();
    float t0 = INF, t1 = INF;
    #pragma unroll
    for (int k = 0; k < 3; ++k) {
        float num0 = vr0[k] - org[k];
        float num1 = vr1[k] - org[k];
        float tmin, tmax;
        if (d[k] == 0.0f) {
            tmin = (num0 > 0.0f) ? INF : -INF;
            tmax = (num1 > 0.0f) ? INF : -INF;
        } else {
            tmin = num0 / d[k];
            tmax = num1 / d[k];
        }
        t0 = fminf(t0, (tmin > 0.0f) ? tmin : INF);
        t1 = fminf(t1, (tmax > 0.0f) ? tmax : INF);
    }
    float t_end   = fminf(t0, t1);
    float t_start = 0.0f;

    // ---- per-(sample,corner) address + trilerp weight (no loads yet) ----
    const size_t CS = (size_t)GRD * GRD * GRD;
    const bool act = (s < NS);
    float  w = 0.0f;
    size_t base = 0;

    if (act) {
        float lin = (float)s / (float)(NS - 1);
        float t = t_start + lin * (t_end - t_start);

        float np_[3];
        #pragma unroll
        for (int k = 0; k < 3; ++k) {
            float p = org[k] + t * d[k];
            np_[k] = (p - vr0[k]) / (vr1[k] - vr0[k]) * 2.0f - 1.0f;
        }
        float ix = (np_[0] + 1.0f) * 0.5f * (float)(GRD - 1);
        float iy = (np_[1] + 1.0f) * 0.5f * (float)(GRD - 1);
        float iz = (np_[2] + 1.0f) * 0.5f * (float)(GRD - 1);
        float x0f = floorf(ix), y0f = floorf(iy), z0f = floorf(iz);
        float fx = ix - x0f, fy = iy - y0f, fz = iz - z0f;
        int x0 = (int)x0f, y0 = (int)y0f, z0 = (int)z0f;

        int cx = corner & 1, cy = (corner >> 1) & 1, cz = corner >> 2;
        int xi = x0 + cx, yi = y0 + cy, zi = z0 + cz;
        w = (cx ? fx : 1.0f - fx)
          * (cy ? fy : 1.0f - fy)
          * (cz ? fz : 1.0f - fz);
        bool valid = ((unsigned)xi < GRD) & ((unsigned)yi < GRD)
                   & ((unsigned)zi < GRD);
        w = valid ? w : 0.0f;
        int xc = iclamp(xi, 0, GRD - 1);
        int yc = iclamp(yi, 0, GRD - 1);
        int zc = iclamp(zi, 0, GRD - 1);
        base = ((size_t)zc * GRD + (size_t)yc) * GRD + (size_t)xc;
    }

    // ---- phase A (chunk): alpha for samples 0..23 only ----
    float alpha_part = 0.0f;
    if (act && wid < CHUNKW)
        alpha_part = w * SGLV[3 * CS + base];

    float alpha = corner_reduce(alpha_part);
    float fac = act ? (1.0f - alpha) + 1e-10f : 1.0f;  // =1 for ungathered
    float p = group_scan(fac, lane);
    if (lane == 63) s_wtot[wid] = p;
    __syncthreads();

    // block-uniform: has transmittance died within the chunk?
    float Tchunk = s_wtot[0] * s_wtot[1] * s_wtot[2];
    bool full = (Tchunk > EPS);

    if (full) {  // rare slow-decay ray: gather the rest, redo scan exactly
        if (act && wid >= CHUNKW)
            alpha_part = w * SGLV[3 * CS + base];
        alpha = corner_reduce(alpha_part);
        fac = act ? (1.0f - alpha) + 1e-10f : 1.0f;
        p = group_scan(fac, lane);
        __syncthreads();            // protect s_wtot re-write
        if (lane == 63) s_wtot[wid] = p;
        __syncthreads();
    }

    float pre = 1.0f;
    for (int w2 = 0; w2 < wid; ++w2) pre *= s_wtot[w2];
    float T   = pre * p;                      // inclusive transmittance
    float wgt = act ? alpha * T : 0.0f;       // uniform across 8 corner lanes
    const bool live = act && (T > EPS);
    // note: for skipped samples (!full, s>=24): alpha=0 -> wgt=0, T=Tchunk<=EPS

    // ---- phase B: gather 10 channels only for live samples ----
    float part[NCH];
    #pragma unroll
    for (int c = 0; c < NCH; ++c) part[c] = 0.0f;
    part[3] = alpha_part;

    if (live) {
        #pragma unroll
        for (int c = 0; c < NCH; ++c) {
            if (c == 3) continue;
            part[c] = w * SGLV[(size_t)c * CS + base];
        }
    }

    // ---- fused corner+sample reduction: sum wgt*part over all 64 lanes ----
    // (wgt uniform per 8-lane group; Σ_s Σ_corner wgt*part = Σ_s wgt*samp)
    if (__any(live)) {
        #pragma unroll
        for (int c = 0; c < NCH; ++c) {
            float val = wgt * part[c];
            #pragma unroll
            for (int off = 32; off > 0; off >>= 1)
                val += __shfl_xor(val, off, 64);
            if (lane == 0) s_red[wid][c] = val;
        }
    } else if (lane == 0) {
        #pragma unroll
        for (int c = 0; c < NCH; ++c) s_red[wid][c] = 0.0f;
    }
    __syncthreads();

    if (tid == 0) {
        float acc[NCH];
        #pragma unroll
        for (int c = 0; c < NCH; ++c) {
            float a = 0.0f;
            #pragma unroll
            for (int w2 = 0; w2 < NW; ++w2) a += s_red[w2][c];
            acc[c] = a;
        }
        float sdd = d[0] * acc[8] + d[1] * acc[9] + d[2] * acc[10];
        float e = expf(acc[7] * (sdd - 1.0f));
        int pix = v * RES_H + u;
        out[0 * RES_V * RES_H + pix] = acc[0] + acc[4] * e;
        out[1 * RES_V * RES_H + pix] = acc[1] + acc[5] * e;
        out[2 * RES_V * RES_H + pix] = acc[2] + acc[6] * e;
    }
}

extern "C" void kernel_launch(void* const* d_in, const int* in_sizes, int n_in,
                              void* d_out, int out_size, void* d_ws, size_t ws_size,
                              hipStream_t stream) {
    const float* origin = (const float*)d_in[0];
    const float* SGLV   = (const float*)d_in[1];
    const float* vrange = (const float*)d_in[2];
    float* out = (float*)d_out;

    sglv_render_kernel<<<dim3(RES_V * RES_H), dim3(BLK), 0, stream>>>(
        origin, SGLV, vrange, out);
}

// Round 5
// 14.014 us; speedup vs baseline: 4.4447x; 1.0805x over previous
//
#include <hip/hip_runtime.h>

#define RES_V 16
#define RES_H 32
#define NS    100
#define GRD   256
#define NCH   11
#define BLK   256           // 4 waves: 32 sample-groups x 8 corners
#define SPECN 16            // speculative all-channel samples (waves 0-1)
#define EPS   1e-5f         // dead-sample threshold

__device__ __forceinline__ int iclamp(int x, int lo, int hi) {
    return x < lo ? lo : (x > hi ? hi : x);
}

__device__ __forceinline__ float corner_reduce(float x) {
    x += __shfl_xor(x, 1, 64);
    x += __shfl_xor(x, 2, 64);
    x += __shfl_xor(x, 4, 64);
    return x;
}

// inclusive product scan across the 8 sample-groups of a wave
// (fac uniform within each 8-lane group)
__device__ __forceinline__ float group_scan(float fac, int lane) {
    float p = fac;
    #pragma unroll
    for (int off = 8; off < 64; off <<= 1) {
        float o = __shfl_up(p, off, 64);
        if (lane >= off) p *= o;
    }
    return p;
}

// One block per ray, 4 waves. Thread = (sample-group sg = tid>>3, corner).
// Chunk loop over samples (32/chunk); chunk 0 speculatively gathers ALL 11
// channels for samples 0..15 and alpha for 16..31 in one parallel burst ->
// single memory round trip for ~87% of rays. Later chunks only run while
// block-uniform running_T > EPS (rare).
__global__ __launch_bounds__(BLK) void sglv_render_kernel(
    const float* __restrict__ origin,
    const float* __restrict__ SGLV,
    const float* __restrict__ vrange,
    float* __restrict__ out)
{
    const int ray    = blockIdx.x;      // 0..511
    const int v      = ray >> 5;
    const int u      = ray & 31;
    const int tid    = threadIdx.x;     // 0..255
    const int lane   = tid & 63;
    const int wid    = tid >> 6;        // 0..3
    const int sg     = tid >> 3;        // sample-group 0..31
    const int corner = tid & 7;         // cx=bit0, cy=bit1, cz=bit2

    __shared__ float s_wtot[4];         // per-wave chunk transmittance factor
    __shared__ float s_red[4][NCH];     // per-wave channel partial sums

    // ---- direction (f32 trig; validated rounds 2-4) ----
    const float PIF = 3.14159265358979323846f;
    float phi   = (2.0f * PIF / (float)RES_H) * (float)u;
    float theta = (PIF / (float)RES_V) * (float)v;
    float stv = sinf(theta);
    float dx0 = stv * cosf(phi);
    float dy0 = cosf(theta);
    float dz0 = stv * sinf(phi);
    float nrm = sqrtf(dx0 * dx0 + dy0 * dy0 + dz0 * dz0);
    nrm = fmaxf(nrm, 1e-12f);
    float d[3] = { dx0 / nrm, dy0 / nrm, dz0 / nrm };

    float org[3] = { origin[0], origin[1], origin[2] };
    float vr0[3] = { vrange[0], vrange[1], vrange[2] };
    float vr1[3] = { vrange[3], vrange[4], vrange[5] };

    // ---- ray-box (reference slab logic incl. strict >0 and +-inf) ----
    const float INF = __builtin_inff();
    float t0 = INF, t1 = INF;
    #pragma unroll
    for (int k = 0; k < 3; ++k) {
        float num0 = vr0[k] - org[k];
        float num1 = vr1[k] - org[k];
        float tmin, tmax;
        if (d[k] == 0.0f) {
            tmin = (num0 > 0.0f) ? INF : -INF;
            tmax = (num1 > 0.0f) ? INF : -INF;
        } else {
            tmin = num0 / d[k];
            tmax = num1 / d[k];
        }
        t0 = fminf(t0, (tmin > 0.0f) ? tmin : INF);
        t1 = fminf(t1, (tmax > 0.0f) ? tmax : INF);
    }
    float t_end   = fminf(t0, t1);
    float t_start = 0.0f;

    const size_t CS = (size_t)GRD * GRD * GRD;

    float acc[NCH];
    #pragma unroll
    for (int c = 0; c < NCH; ++c) acc[c] = 0.0f;
    float running_T = 1.0f;             // block-uniform

    for (int s0 = 0; s0 < NS; s0 += 32) {
        const int  s   = s0 + sg;
        const bool act = (s < NS);

        // ---- address + trilerp weight for this sample ----
        float  w = 0.0f;
        size_t base = 0;
        if (act) {
            float lin = (float)s / (float)(NS - 1);
            float t = t_start + lin * (t_end - t_start);
            float np_[3];
            #pragma unroll
            for (int k = 0; k < 3; ++k) {
                float p = org[k] + t * d[k];
                np_[k] = (p - vr0[k]) / (vr1[k] - vr0[k]) * 2.0f - 1.0f;
            }
            float ix = (np_[0] + 1.0f) * 0.5f * (float)(GRD - 1);
            float iy = (np_[1] + 1.0f) * 0.5f * (float)(GRD - 1);
            float iz = (np_[2] + 1.0f) * 0.5f * (float)(GRD - 1);
            float x0f = floorf(ix), y0f = floorf(iy), z0f = floorf(iz);
            float fx = ix - x0f, fy = iy - y0f, fz = iz - z0f;
            int x0 = (int)x0f, y0 = (int)y0f, z0 = (int)z0f;
            int cx = corner & 1, cy = (corner >> 1) & 1, cz = corner >> 2;
            int xi = x0 + cx, yi = y0 + cy, zi = z0 + cz;
            w = (cx ? fx : 1.0f - fx)
              * (cy ? fy : 1.0f - fy)
              * (cz ? fz : 1.0f - fz);
            bool valid = ((unsigned)xi < GRD) & ((unsigned)yi < GRD)
                       & ((unsigned)zi < GRD);
            w = valid ? w : 0.0f;
            int xc = iclamp(xi, 0, GRD - 1);
            int yc = iclamp(yi, 0, GRD - 1);
            int zc = iclamp(zi, 0, GRD - 1);
            base = ((size_t)zc * GRD + (size_t)yc) * GRD + (size_t)xc;
        }

        // ---- one parallel load burst ----
        float part[NCH];
        #pragma unroll
        for (int c = 0; c < NCH; ++c) part[c] = 0.0f;
        const bool spec = (s0 == 0) && (s < SPECN);   // wave-uniform
        if (act) {
            if (spec) {
                #pragma unroll
                for (int c = 0; c < NCH; ++c)
                    part[c] = w * SGLV[(size_t)c * CS + base];
            } else {
                part[3] = w * SGLV[3 * CS + base];
            }
        }

        // ---- cumprod scan over this chunk ----
        float alpha = corner_reduce(part[3]);
        float fac = act ? (1.0f - alpha) + 1e-10f : 1.0f;
        float p = group_scan(fac, lane);
        if (lane == 63) s_wtot[wid] = p;
        __syncthreads();

        float pre = running_T;
        for (int w2 = 0; w2 < wid; ++w2) pre *= s_wtot[w2];
        float chunk_prod = s_wtot[0] * s_wtot[1] * s_wtot[2] * s_wtot[3];
        float T   = pre * p;                    // inclusive transmittance
        float wgt = act ? alpha * T : 0.0f;     // uniform across corner lanes
        const bool live = act && (T > EPS);

        // non-speculated live samples: gather remaining channels (rare)
        if (live && !spec) {
            #pragma unroll
            for (int c = 0; c < NCH; ++c) {
                if (c == 3) continue;
                part[c] = w * SGLV[(size_t)c * CS + base];
            }
        }

        // accumulate (channel 3 never used by the epilogue -> skipped);
        // spec threads accumulate exactly regardless of live (values in hand)
        #pragma unroll
        for (int c = 0; c < NCH; ++c) {
            if (c == 3) continue;
            acc[c] += wgt * part[c];
        }

        running_T *= chunk_prod;                // block-uniform
        __syncthreads();                        // protect s_wtot for next iter
        if (running_T <= EPS) break;            // block-uniform exit
    }

    // ---- single fused reduction: sum acc over all 64 lanes, 4 waves ----
    #pragma unroll
    for (int c = 0; c < NCH; ++c) {
        if (c == 3) continue;
        float val = acc[c];
        #pragma unroll
        for (int off = 32; off > 0; off >>= 1)
            val += __shfl_xor(val, off, 64);
        if (lane == 0) s_red[wid][c] = val;
    }
    __syncthreads();

    if (tid == 0) {
        float a[NCH];
        #pragma unroll
        for (int c = 0; c < NCH; ++c) {
            if (c == 3) { a[c] = 0.0f; continue; }
            a[c] = s_red[0][c] + s_red[1][c] + s_red[2][c] + s_red[3][c];
        }
        float sdd = d[0] * a[8] + d[1] * a[9] + d[2] * a[10];
        float e = expf(a[7] * (sdd - 1.0f));
        int pix = v * RES_H + u;
        out[0 * RES_V * RES_H + pix] = a[0] + a[4] * e;
        out[1 * RES_V * RES_H + pix] = a[1] + a[5] * e;
        out[2 * RES_V * RES_H + pix] = a[2] + a[6] * e;
    }
}

extern "C" void kernel_launch(void* const* d_in, const int* in_sizes, int n_in,
                              void* d_out, int out_size, void* d_ws, size_t ws_size,
                              hipStream_t stream) {
    const float* origin = (const float*)d_in[0];
    const float* SGLV   = (const float*)d_in[1];
    const float* vrange = (const float*)d_in[2];
    float* out = (float*)d_out;

    sglv_render_kernel<<<dim3(RES_V * RES_H), dim3(BLK), 0, stream>>>(
        origin, SGLV, vrange, out);
}

// Round 6
// 13.976 us; speedup vs baseline: 4.4567x; 1.0027x over previous
//
#include <hip/hip_runtime.h>

#define RES_V 16
#define RES_H 32
#define NS    100
#define GRD   256
#define NCH   11
#define BLK   512           // 8 waves: 32 sample-groups x 2 channel-halves x 8 corners
#define SPECN 16            // speculative all-channel samples
#define EPS   1e-5f         // dead-sample threshold

__device__ __forceinline__ int iclamp(int x, int lo, int hi) {
    return x < lo ? lo : (x > hi ? hi : x);
}

// One block per ray, 8 waves, 512 threads.
// tid = sg*16 + h*8 + corner:  sg = sample-group 0..31, h = channel-half,
// corner bits: cx=bit0, cy=bit1, cz=bit2.
// Channel half A (h=0): {3,0,1,2,4} (alpha first), half B (h=1): {5..10}.
// Chunk 0 speculatively gathers the half-set for samples 0..15 and alpha for
// 16..31 in one parallel burst; later chunks alpha-only + rare live fallback.
__global__ __launch_bounds__(BLK) void sglv_render_kernel(
    const float* __restrict__ origin,
    const float* __restrict__ SGLV,
    const float* __restrict__ vrange,
    float* __restrict__ out)
{
    const int ray    = blockIdx.x;      // 0..511
    const int v      = ray >> 5;
    const int u      = ray & 31;
    const int tid    = threadIdx.x;     // 0..511
    const int lane   = tid & 63;
    const int wid    = tid >> 6;        // 0..7
    const int corner = tid & 7;
    const int h      = (tid >> 3) & 1;
    const int sg     = tid >> 4;        // 0..31

    __shared__ float s_wtot[8];         // per-wave chunk transmittance factor
    __shared__ float s_red[8][NCH];     // per-wave channel partial sums

    // my channel set (compile-time; fully unrolled indexing stays in regs)
    const int chA[5] = {3, 0, 1, 2, 4};
    const int chB[6] = {5, 6, 7, 8, 9, 10};
    const int nmine  = h ? 6 : 5;

    // ---- direction (f32 trig; validated rounds 2-5) ----
    const float PIF = 3.14159265358979323846f;
    float phi   = (2.0f * PIF / (float)RES_H) * (float)u;
    float theta = (PIF / (float)RES_V) * (float)v;
    float stv = sinf(theta);
    float dx0 = stv * cosf(phi);
    float dy0 = cosf(theta);
    float dz0 = stv * sinf(phi);
    float nrm = sqrtf(dx0 * dx0 + dy0 * dy0 + dz0 * dz0);
    nrm = fmaxf(nrm, 1e-12f);
    float d[3] = { dx0 / nrm, dy0 / nrm, dz0 / nrm };

    float org[3] = { origin[0], origin[1], origin[2] };
    float vr0[3] = { vrange[0], vrange[1], vrange[2] };
    float vr1[3] = { vrange[3], vrange[4], vrange[5] };

    // ---- ray-box (reference slab logic incl. strict >0 and +-inf) ----
    const float INF = __builtin_inff();
    float t0 = INF, t1 = INF;
    #pragma unroll
    for (int k = 0; k < 3; ++k) {
        float num0 = vr0[k] - org[k];
        float num1 = vr1[k] - org[k];
        float tmin, tmax;
        if (d[k] == 0.0f) {
            tmin = (num0 > 0.0f) ? INF : -INF;
            tmax = (num1 > 0.0f) ? INF : -INF;
        } else {
            tmin = num0 / d[k];
            tmax = num1 / d[k];
        }
        t0 = fminf(t0, (tmin > 0.0f) ? tmin : INF);
        t1 = fminf(t1, (tmax > 0.0f) ? tmax : INF);
    }
    float t_end   = fminf(t0, t1);
    float t_start = 0.0f;

    const size_t CS = (size_t)GRD * GRD * GRD;

    float accL[6];                      // my channel-half accumulators
    #pragma unroll
    for (int i = 0; i < 6; ++i) accL[i] = 0.0f;
    float running_T = 1.0f;             // block-uniform

    for (int s0 = 0; s0 < NS; s0 += 32) {
        const int  s   = s0 + sg;
        const bool act = (s < NS);

        // ---- address + trilerp weight (duplicated across h; VALU-cheap) ----
        float  w = 0.0f;
        size_t base = 0;
        if (act) {
            float lin = (float)s / (float)(NS - 1);
            float t = t_start + lin * (t_end - t_start);
            float np_[3];
            #pragma unroll
            for (int k = 0; k < 3; ++k) {
                float p = org[k] + t * d[k];
                np_[k] = (p - vr0[k]) / (vr1[k] - vr0[k]) * 2.0f - 1.0f;
            }
            float ix = (np_[0] + 1.0f) * 0.5f * (float)(GRD - 1);
            float iy = (np_[1] + 1.0f) * 0.5f * (float)(GRD - 1);
            float iz = (np_[2] + 1.0f) * 0.5f * (float)(GRD - 1);
            float x0f = floorf(ix), y0f = floorf(iy), z0f = floorf(iz);
            float fx = ix - x0f, fy = iy - y0f, fz = iz - z0f;
            int x0 = (int)x0f, y0 = (int)y0f, z0 = (int)z0f;
            int cx = corner & 1, cy = (corner >> 1) & 1, cz = corner >> 2;
            int xi = x0 + cx, yi = y0 + cy, zi = z0 + cz;
            w = (cx ? fx : 1.0f - fx)
              * (cy ? fy : 1.0f - fy)
              * (cz ? fz : 1.0f - fz);
            bool valid = ((unsigned)xi < GRD) & ((unsigned)yi < GRD)
                       & ((unsigned)zi < GRD);
            w = valid ? w : 0.0f;
            int xc = iclamp(xi, 0, GRD - 1);
            int yc = iclamp(yi, 0, GRD - 1);
            int zc = iclamp(zi, 0, GRD - 1);
            base = ((size_t)zc * GRD + (size_t)yc) * GRD + (size_t)xc;
        }

        // ---- one parallel load burst (<=6 loads/thread) ----
        float part[6];
        #pragma unroll
        for (int i = 0; i < 6; ++i) part[i] = 0.0f;
        const bool spec = (s0 == 0) && (s < SPECN);
        if (act) {
            if (spec) {
                if (h == 0) {
                    #pragma unroll
                    for (int i = 0; i < 5; ++i)
                        part[i] = w * SGLV[(size_t)chA[i] * CS + base];
                } else {
                    #pragma unroll
                    for (int i = 0; i < 6; ++i)
                        part[i] = w * SGLV[(size_t)chB[i] * CS + base];
                }
            } else if (h == 0) {
                part[0] = w * SGLV[3 * CS + base];   // alpha only
            }
        }

        // ---- alpha: corner-reduce within h=0 group, broadcast to h=1 ----
        float alpha = part[0];                 // h=0: w*ch3; h=1: garbage->fixed
        alpha += __shfl_xor(alpha, 1, 64);
        alpha += __shfl_xor(alpha, 2, 64);
        alpha += __shfl_xor(alpha, 4, 64);
        float aswap = __shfl_xor(alpha, 8, 64);
        alpha = h ? aswap : alpha;             // 16-lane supergroup uniform

        // ---- cumprod scan: 4 supergroups/wave (offsets 16,32) + LDS ----
        float fac = act ? (1.0f - alpha) + 1e-10f : 1.0f;
        float p = fac;
        {
            float o = __shfl_up(p, 16, 64); if (lane >= 16) p *= o;
            o       = __shfl_up(p, 32, 64); if (lane >= 32) p *= o;
        }
        if (lane == 63) s_wtot[wid] = p;
        __syncthreads();

        float pre = running_T;
        for (int w2 = 0; w2 < wid; ++w2) pre *= s_wtot[w2];
        float chunk_prod = s_wtot[0] * s_wtot[1] * s_wtot[2] * s_wtot[3]
                         * s_wtot[4] * s_wtot[5] * s_wtot[6] * s_wtot[7];
        float T   = pre * p;                   // inclusive transmittance
        float wgt = act ? alpha * T : 0.0f;
        const bool live = act && (T > EPS);

        // ---- rare fallback: live non-spec samples gather their half ----
        if (live && !spec) {
            const int start = (h == 0) ? 1 : 0;     // h=0 already has ch3
            if (h == 0) {
                #pragma unroll
                for (int i = 1; i < 5; ++i)
                    part[i] = w * SGLV[(size_t)chA[i] * CS + base];
            } else {
                #pragma unroll
                for (int i = 0; i < 6; ++i)
                    part[i] = w * SGLV[(size_t)chB[i] * CS + base];
            }
            (void)start;
        }

        // ---- accumulate (spec threads exact regardless of live) ----
        #pragma unroll
        for (int i = 0; i < 6; ++i)
            accL[i] += wgt * part[i];

        running_T *= chunk_prod;
        __syncthreads();                       // protect s_wtot next iter
        if (running_T <= EPS) break;           // block-uniform exit
    }

    // ---- masked butterfly: reduce over corner+sg bits, NOT the h bit ----
    #pragma unroll
    for (int i = 0; i < 6; ++i) {
        float val = accL[i];
        val += __shfl_xor(val, 1, 64);
        val += __shfl_xor(val, 2, 64);
        val += __shfl_xor(val, 4, 64);
        val += __shfl_xor(val, 16, 64);
        val += __shfl_xor(val, 32, 64);
        accL[i] = val;                         // lanes 0(h=0) / 8(h=1) hold sums
    }
    if (lane == 0) {
        #pragma unroll
        for (int i = 0; i < 5; ++i) s_red[wid][chA[i]] = accL[i];
    }
    if (lane == 8) {
        #pragma unroll
        for (int i = 0; i < 6; ++i) s_red[wid][chB[i]] = accL[i];
    }
    __syncthreads();

    if (tid == 0) {
        float a[NCH];
        #pragma unroll
        for (int c = 0; c < NCH; ++c) {
            float x = 0.0f;
            #pragma unroll
            for (int w2 = 0; w2 < 8; ++w2) x += s_red[w2][c];
            a[c] = x;
        }
        float sdd = d[0] * a[8] + d[1] * a[9] + d[2] * a[10];
        float e = expf(a[7] * (sdd - 1.0f));
        int pix = v * RES_H + u;
        out[0 * RES_V * RES_H + pix] = a[0] + a[4] * e;
        out[1 * RES_V * RES_H + pix] = a[1] + a[5] * e;
        out[2 * RES_V * RES_H + pix] = a[2] + a[6] * e;
    }
}

extern "C" void kernel_launch(void* const* d_in, const int* in_sizes, int n_in,
                              void* d_out, int out_size, void* d_ws, size_t ws_size,
                              hipStream_t stream) {
    const float* origin = (const float*)d_in[0];
    const float* SGLV   = (const float*)d_in[1];
    const float* vrange = (const float*)d_in[2];
    float* out = (float*)d_out;

    sglv_render_kernel<<<dim3(RES_V * RES_H), dim3(BLK), 0, stream>>>(
        origin, SGLV, vrange, out);
}

// Round 7
// 13.121 us; speedup vs baseline: 4.7471x; 1.0652x over previous
//
#include <hip/hip_runtime.h>

#define RES_V 16
#define RES_H 32
#define NS    100
#define GRD   256
#define NCH   11
#define BLK   256           // 16 sample-groups x 2 channel-halves x 8 corners
#define CHUNK 16
#define EPS   1e-5f         // dead-sample threshold

__device__ __forceinline__ int iclamp(int x, int lo, int hi) {
    return x < lo ? lo : (x > hi ? hi : x);
}

// One block per ray, 4 waves, 256 threads.
// tid = sg*16 + h*8 + corner:  sg = sample-in-chunk 0..15, h = channel-half,
// corner bits: cx=bit0, cy=bit1, cz=bit2.
// Half A (h=0): {3,0,1,2,4} (alpha first), half B (h=1): {5..10}.
// Chunk 0 gathers ALL channels for samples 0..15 in one burst (exact, single
// memory round trip). ~87% of rays have T_15 <= EPS and exit immediately.
// Later chunks: alpha-only + rare live fallback.
__global__ __launch_bounds__(BLK) void sglv_render_kernel(
    const float* __restrict__ origin,
    const float* __restrict__ SGLV,
    const float* __restrict__ vrange,
    float* __restrict__ out)
{
    const int ray    = blockIdx.x;      // 0..511
    const int v      = ray >> 5;
    const int u      = ray & 31;
    const int tid    = threadIdx.x;     // 0..255
    const int lane   = tid & 63;
    const int wid    = tid >> 6;        // 0..3
    const int corner = tid & 7;
    const int h      = (tid >> 3) & 1;
    const int sg     = tid >> 4;        // 0..15

    __shared__ float s_wtot[4];         // per-wave chunk transmittance factor
    __shared__ float s_red[4][NCH];     // per-wave channel partial sums

    const int chA[5] = {3, 0, 1, 2, 4};
    const int chB[6] = {5, 6, 7, 8, 9, 10};

    // ---- direction (f32 trig; validated rounds 2-6) ----
    const float PIF = 3.14159265358979323846f;
    float phi   = (2.0f * PIF / (float)RES_H) * (float)u;
    float theta = (PIF / (float)RES_V) * (float)v;
    float stv = sinf(theta);
    float dx0 = stv * cosf(phi);
    float dy0 = cosf(theta);
    float dz0 = stv * sinf(phi);
    float nrm = sqrtf(dx0 * dx0 + dy0 * dy0 + dz0 * dz0);
    nrm = fmaxf(nrm, 1e-12f);
    float d[3] = { dx0 / nrm, dy0 / nrm, dz0 / nrm };

    float org[3] = { origin[0], origin[1], origin[2] };
    float vr0[3] = { vrange[0], vrange[1], vrange[2] };
    float vr1[3] = { vrange[3], vrange[4], vrange[5] };

    // ---- ray-box (reference slab logic incl. strict >0 and +-inf) ----
    const float INF = __builtin_inff();
    float t0 = INF, t1 = INF;
    #pragma unroll
    for (int k = 0; k < 3; ++k) {
        float num0 = vr0[k] - org[k];
        float num1 = vr1[k] - org[k];
        float tmin, tmax;
        if (d[k] == 0.0f) {
            tmin = (num0 > 0.0f) ? INF : -INF;
            tmax = (num1 > 0.0f) ? INF : -INF;
        } else {
            tmin = num0 / d[k];
            tmax = num1 / d[k];
        }
        t0 = fminf(t0, (tmin > 0.0f) ? tmin : INF);
        t1 = fminf(t1, (tmax > 0.0f) ? tmax : INF);
    }
    float t_end   = fminf(t0, t1);
    float t_start = 0.0f;

    // grid-space ray: idx_k(t) = (org+t*d - vr0) * scale_k
    float scale[3], gorg[3], gdir[3];
    #pragma unroll
    for (int k = 0; k < 3; ++k) {
        scale[k] = (float)(GRD - 1) / (vr1[k] - vr0[k]);
        gorg[k]  = (org[k] - vr0[k]) * scale[k];
        gdir[k]  = d[k] * scale[k];
    }
    const float dt = (t_end - t_start) * (1.0f / (float)(NS - 1));

    const size_t CS = (size_t)GRD * GRD * GRD;

    float accL[6];
    #pragma unroll
    for (int i = 0; i < 6; ++i) accL[i] = 0.0f;
    float running_T = 1.0f;             // block-uniform

    for (int s0 = 0; s0 < NS; s0 += CHUNK) {
        const int  s   = s0 + sg;
        const bool act = (s < NS);

        // ---- address + trilerp weight ----
        float  w = 0.0f;
        size_t base = 0;
        if (act) {
            float t = t_start + (float)s * dt;
            float ix = gorg[0] + t * gdir[0];
            float iy = gorg[1] + t * gdir[1];
            float iz = gorg[2] + t * gdir[2];
            float x0f = floorf(ix), y0f = floorf(iy), z0f = floorf(iz);
            float fx = ix - x0f, fy = iy - y0f, fz = iz - z0f;
            int x0 = (int)x0f, y0 = (int)y0f, z0 = (int)z0f;
            int cx = corner & 1, cy = (corner >> 1) & 1, cz = corner >> 2;
            int xi = x0 + cx, yi = y0 + cy, zi = z0 + cz;
            w = (cx ? fx : 1.0f - fx)
              * (cy ? fy : 1.0f - fy)
              * (cz ? fz : 1.0f - fz);
            bool valid = ((unsigned)xi < GRD) & ((unsigned)yi < GRD)
                       & ((unsigned)zi < GRD);
            w = valid ? w : 0.0f;
            int xc = iclamp(xi, 0, GRD - 1);
            int yc = iclamp(yi, 0, GRD - 1);
            int zc = iclamp(zi, 0, GRD - 1);
            base = ((size_t)zc * GRD + (size_t)yc) * GRD + (size_t)xc;
        }

        // ---- load burst ----
        float part[6];
        #pragma unroll
        for (int i = 0; i < 6; ++i) part[i] = 0.0f;
        const bool spec = (s0 == 0);            // chunk 0: full speculation
        if (act) {
            if (spec) {
                if (h == 0) {
                    #pragma unroll
                    for (int i = 0; i < 5; ++i)
                        part[i] = w * SGLV[(size_t)chA[i] * CS + base];
                } else {
                    #pragma unroll
                    for (int i = 0; i < 6; ++i)
                        part[i] = w * SGLV[(size_t)chB[i] * CS + base];
                }
            } else if (h == 0) {
                part[0] = w * SGLV[3 * CS + base];   // alpha only
            }
        }

        // ---- alpha: corner-reduce (h=0), broadcast to h=1 ----
        float alpha = part[0];
        alpha += __shfl_xor(alpha, 1, 64);
        alpha += __shfl_xor(alpha, 2, 64);
        alpha += __shfl_xor(alpha, 4, 64);
        float aswap = __shfl_xor(alpha, 8, 64);
        alpha = h ? aswap : alpha;              // 16-lane supergroup uniform

        // ---- cumprod scan: shfl_up 16,32 within wave + LDS cross-wave ----
        float fac = act ? (1.0f - alpha) + 1e-10f : 1.0f;
        float p = fac;
        {
            float o = __shfl_up(p, 16, 64); if (lane >= 16) p *= o;
            o       = __shfl_up(p, 32, 64); if (lane >= 32) p *= o;
        }
        if (lane == 63) s_wtot[wid] = p;
        __syncthreads();

        float pre = running_T;
        for (int w2 = 0; w2 < wid; ++w2) pre *= s_wtot[w2];
        float chunk_prod = s_wtot[0] * s_wtot[1] * s_wtot[2] * s_wtot[3];
        float T   = pre * p;                    // inclusive transmittance
        float wgt = act ? alpha * T : 0.0f;
        const bool live = act && (T > EPS);

        // ---- rare fallback: live non-spec samples gather their half ----
        if (live && !spec) {
            if (h == 0) {
                #pragma unroll
                for (int i = 1; i < 5; ++i)
                    part[i] = w * SGLV[(size_t)chA[i] * CS + base];
            } else {
                #pragma unroll
                for (int i = 0; i < 6; ++i)
                    part[i] = w * SGLV[(size_t)chB[i] * CS + base];
            }
        }

        // ---- accumulate (chunk-0 threads exact regardless of live) ----
        #pragma unroll
        for (int i = 0; i < 6; ++i)
            accL[i] += wgt * part[i];

        running_T *= chunk_prod;
        __syncthreads();                        // protect s_wtot next iter
        if (running_T <= EPS) break;            // block-uniform exit
    }

    // ---- masked butterfly: reduce over corner+sg bits, NOT the h bit ----
    #pragma unroll
    for (int i = 0; i < 6; ++i) {
        float val = accL[i];
        val += __shfl_xor(val, 1, 64);
        val += __shfl_xor(val, 2, 64);
        val += __shfl_xor(val, 4, 64);
        val += __shfl_xor(val, 16, 64);
        val += __shfl_xor(val, 32, 64);
        accL[i] = val;                          // lane 0 (h=0) / 8 (h=1)
    }
    if (lane == 0) {
        #pragma unroll
        for (int i = 0; i < 5; ++i) s_red[wid][chA[i]] = accL[i];
    }
    if (lane == 8) {
        #pragma unroll
        for (int i = 0; i < 6; ++i) s_red[wid][chB[i]] = accL[i];
    }
    __syncthreads();

    if (tid == 0) {
        float a[NCH];
        #pragma unroll
        for (int c = 0; c < NCH; ++c)
            a[c] = s_red[0][c] + s_red[1][c] + s_red[2][c] + s_red[3][c];
        float sdd = d[0] * a[8] + d[1] * a[9] + d[2] * a[10];
        float e = expf(a[7] * (sdd - 1.0f));
        int pix = v * RES_H + u;
        out[0 * RES_V * RES_H + pix] = a[0] + a[4] * e;
        out[1 * RES_V * RES_H + pix] = a[1] + a[5] * e;
        out[2 * RES_V * RES_H + pix] = a[2] + a[6] * e;
    }
}

extern "C" void kernel_launch(void* const* d_in, const int* in_sizes, int n_in,
                              void* d_out, int out_size, void* d_ws, size_t ws_size,
                              hipStream_t stream) {
    const float* origin = (const float*)d_in[0];
    const float* SGLV   = (const float*)d_in[1];
    const float* vrange = (const float*)d_in[2];
    float* out = (float*)d_out;

    sglv_render_kernel<<<dim3(RES_V * RES_H), dim3(BLK), 0, stream>>>(
        origin, SGLV, vrange, out);
}